// Round 3
// baseline (290.431 us; speedup 1.0000x reference)
//
#include <hip/hip_runtime.h>
#include <hip/hip_bf16.h>

#define N_ROWS 32768
#define M_ROWS 8192
#define D_DIM  384
#define K_NB   9
#define BN     64
#define MQ     (M_ROWS / 4)      // 2048 cols per block
#define TILES  (MQ / BN)         // 32
#define KSTEPS (D_DIM / 32)      // 12

#define QRANGE 2048.0f
#define QSCALE (1.0f / 2048.0f)
#define QSTEPF (QRANGE / 65535.0f)
#define M2S    (-2.0f * QSCALE)
#define BIGF   3.0e38f

typedef __attribute__((ext_vector_type(8))) short short8;
typedef __attribute__((ext_vector_type(4))) float f32x4;
typedef __attribute__((ext_vector_type(2))) unsigned short u16x2;

// ---------------- prep: f32 -> bf16 copies + f32 row norms ----------------
__global__ __launch_bounds__(256) void FAPM_prep(
    const float* __restrict__ emb, const float* __restrict__ mem,
    __hip_bfloat16* __restrict__ Ab, __hip_bfloat16* __restrict__ Bb,
    float* __restrict__ xn, float* __restrict__ yn) {
  const int lane = threadIdx.x & 63;
  const int row  = blockIdx.x * 4 + (threadIdx.x >> 6);
  const float* src;
  __hip_bfloat16* dst;
  float* nptr;
  if (row < N_ROWS) {
    src = emb + (size_t)row * D_DIM; dst = Ab + (size_t)row * D_DIM; nptr = xn + row;
  } else {
    int r = row - N_ROWS;
    src = mem + (size_t)r * D_DIM; dst = Bb + (size_t)r * D_DIM; nptr = yn + r;
  }
  float s = 0.f;
#pragma unroll
  for (int j = 0; j < 6; ++j) {
    float v = src[j * 64 + lane];
    s += v * v;
    dst[j * 64 + lane] = __float2bfloat16(v);
  }
#pragma unroll
  for (int dd = 1; dd < 64; dd <<= 1) s += __shfl_xor(s, dd);
  if (lane == 0) *nptr = s;
}

// ---- 16-lane merge of per-lane sorted u16 lists; writes f32 d^2 ascending ----
__device__ __forceinline__ void merge16i(unsigned t[9], float* dst, int sub) {
  for (int s = 0; s < K_NB; ++s) {
    unsigned m  = t[0];
    int      ml = sub;
#pragma unroll
    for (int dd = 1; dd < 16; dd <<= 1) {
      unsigned ov = (unsigned)__shfl_xor((int)m, dd);
      int      ol = __shfl_xor(ml, dd);
      bool take = (ov < m) || (ov == m && ol < ml);
      m  = take ? ov : m;
      ml = take ? ol : ml;
    }
    if (sub == ml) {  // owner pops its head
#pragma unroll
      for (int j = 0; j < 8; ++j) t[j] = t[j + 1];
      t[8] = 0xFFFFu;
    }
    if (sub == 0) dst[s] = (float)m * QSTEPF;
  }
}

// ------- fused: bf16 MFMA d^2 + packed-u16 top-9, quarter of M -------
__global__ __launch_bounds__(256)
__attribute__((amdgpu_waves_per_eu(2, 2)))
void FAPM_fused(
    const __hip_bfloat16* __restrict__ Ab, const __hip_bfloat16* __restrict__ Bb,
    const float* __restrict__ xn, const float* __restrict__ yn,
    float* __restrict__ part) {
  // B tile 64x384 bf16 as 48 contiguous 1KB subtiles [cb*12+kk];
  // within a subtile, chunk for (row r, kpart p) lives at byte (p*16+r)*16,
  // so reader lane l (row=l&15, kpart=l>>4) reads at lane*16: conflict-free.
  __shared__ __attribute__((aligned(128))) unsigned char Bs[48 * 1024];
  const int tid  = threadIdx.x;
  const int lane = tid & 63;
  const int w    = tid >> 6;          // wave 0..3
  const int sub  = lane & 15;
  const int grp  = lane >> 4;
  const int bx   = blockIdx.x;
  const int mq   = bx & 3;            // which M-quarter
  const int wrow0 = (bx >> 2) * 128 + w * 32;  // wave owns 32 rows
  const int colbase = mq * MQ;

  // A fragments in registers: 2 row-blocks of 16
  short8 af0[KSTEPS], af1[KSTEPS];
  {
    const __hip_bfloat16* ap0 = Ab + (size_t)(wrow0 + sub) * D_DIM + grp * 8;
    const __hip_bfloat16* ap1 = ap0 + 16 * D_DIM;
#pragma unroll
    for (int kk = 0; kk < KSTEPS; ++kk) {
      af0[kk] = *(const short8*)(ap0 + kk * 32);
      af1[kk] = *(const short8*)(ap1 + kk * 32);
    }
  }
  // pre-scaled x-norms for this lane's rows (C/D layout: row = grp*4 + i)
  float xs0[4], xs1[4];
#pragma unroll
  for (int i = 0; i < 4; ++i) {
    xs0[i] = xn[wrow0 + grp * 4 + i] * QSCALE;
    xs1[i] = xn[wrow0 + 16 + grp * 4 + i] * QSCALE;
  }

  u16x2 tkp[4][9];  // packed (rowblock0, rowblock1) top-9 in quantized d^2
#pragma unroll
  for (int i = 0; i < 4; ++i)
#pragma unroll
    for (int j = 0; j < 9; ++j) { tkp[i][j].x = 0xFFFFu; tkp[i][j].y = 0xFFFFu; }

  // staging source mapping: lane l fetches (row = l&15, kpart = l>>4)
  const int s_row = lane & 15;
  const int s_kof = (lane >> 4) * 8;
  const unsigned char* bread = Bs + lane * 16;

  for (int t = 0; t < TILES; ++t) {
    const int col0 = colbase + t * BN;
    const __hip_bfloat16* bsrc =
        Bb + (size_t)(col0 + w * 16 + s_row) * D_DIM + s_kof;
#pragma unroll
    for (int q = 0; q < KSTEPS; ++q) {
      __builtin_amdgcn_global_load_lds(
          (const __attribute__((address_space(1))) void*)(bsrc + q * 32),
          (__attribute__((address_space(3))) void*)(Bs + (w * KSTEPS + q) * 1024),
          16, 0, 0);
    }
    float ysv[4];
#pragma unroll
    for (int cb = 0; cb < 4; ++cb) ysv[cb] = yn[col0 + cb * 16 + sub] * QSCALE;
    asm volatile("s_waitcnt vmcnt(0)" ::: "memory");
    __syncthreads();

#pragma unroll
    for (int cbp = 0; cbp < 2; ++cbp) {
      const int cbA = 2 * cbp, cbB = 2 * cbp + 1;
      f32x4 a00 = {0.f,0.f,0.f,0.f}, a10 = {0.f,0.f,0.f,0.f};
      f32x4 a01 = {0.f,0.f,0.f,0.f}, a11 = {0.f,0.f,0.f,0.f};
#pragma unroll
      for (int kk = 0; kk < KSTEPS; ++kk) {
        short8 bf0 = *(const short8*)(bread + (cbA * KSTEPS + kk) * 1024);
        short8 bf1 = *(const short8*)(bread + (cbB * KSTEPS + kk) * 1024);
        a00 = __builtin_amdgcn_mfma_f32_16x16x32_bf16(af0[kk], bf0, a00, 0, 0, 0);
        a10 = __builtin_amdgcn_mfma_f32_16x16x32_bf16(af1[kk], bf0, a10, 0, 0, 0);
        a01 = __builtin_amdgcn_mfma_f32_16x16x32_bf16(af0[kk], bf1, a01, 0, 0, 0);
        a11 = __builtin_amdgcn_mfma_f32_16x16x32_bf16(af1[kk], bf1, a11, 0, 0, 0);
      }
#pragma unroll
      for (int i = 0; i < 4; ++i) {
        {
          float d2a = fmaf(a00[i], M2S, xs0[i] + ysv[cbA]);
          float d2b = fmaf(a10[i], M2S, xs1[i] + ysv[cbA]);
          unsigned dpu;
          asm("v_cvt_pknorm_u16_f32 %0, %1, %2" : "=v"(dpu) : "v"(d2a), "v"(d2b));
          u16x2 dp = __builtin_bit_cast(u16x2, dpu);
#pragma unroll
          for (int j = 8; j >= 1; --j)
            tkp[i][j] = __builtin_elementwise_min(
                tkp[i][j], __builtin_elementwise_max(dp, tkp[i][j - 1]));
          tkp[i][0] = __builtin_elementwise_min(tkp[i][0], dp);
        }
        {
          float d2a = fmaf(a01[i], M2S, xs0[i] + ysv[cbB]);
          float d2b = fmaf(a11[i], M2S, xs1[i] + ysv[cbB]);
          unsigned dpu;
          asm("v_cvt_pknorm_u16_f32 %0, %1, %2" : "=v"(dpu) : "v"(d2a), "v"(d2b));
          u16x2 dp = __builtin_bit_cast(u16x2, dpu);
#pragma unroll
          for (int j = 8; j >= 1; --j)
            tkp[i][j] = __builtin_elementwise_min(
                tkp[i][j], __builtin_elementwise_max(dp, tkp[i][j - 1]));
          tkp[i][0] = __builtin_elementwise_min(tkp[i][0], dp);
        }
      }
    }
    __syncthreads();
  }

  // ---- unpack + per-row merge across 16 sub-lanes; write f32 d^2 partials ----
  float* pbase = part + (size_t)mq * N_ROWS * K_NB;
#pragma unroll
  for (int i = 0; i < 4; ++i) {
    unsigned ta[9], tb[9];
#pragma unroll
    for (int j = 0; j < 9; ++j) { ta[j] = tkp[i][j].x; tb[j] = tkp[i][j].y; }
    merge16i(ta, pbase + (size_t)(wrow0 + grp * 4 + i) * K_NB, sub);
    merge16i(tb, pbase + (size_t)(wrow0 + 16 + grp * 4 + i) * K_NB, sub);
  }
}

// ------- merge the four M-quarter partials, sqrt, final output -------
__global__ __launch_bounds__(256) void FAPM_merge4(
    const float* __restrict__ part, float* __restrict__ out) {
  const int r = blockIdx.x * 256 + threadIdx.x;
  float l[4][9];
#pragma unroll
  for (int q = 0; q < 4; ++q)
#pragma unroll
    for (int j = 0; j < 9; ++j)
      l[q][j] = part[(size_t)q * N_ROWS * K_NB + (size_t)r * K_NB + j];
#pragma unroll
  for (int s = 0; s < K_NB; ++s) {
    float m = fminf(fminf(l[0][0], l[1][0]), fminf(l[2][0], l[3][0]));
    out[(size_t)r * K_NB + s] = sqrtf(m);
    bool t0 = (l[0][0] == m);
    bool t1 = (l[1][0] == m) && !t0;
    bool t2 = (l[2][0] == m) && !t0 && !t1;
    bool t3 = !(t0 || t1 || t2);
#pragma unroll
    for (int j = 0; j < 8; ++j) {
      l[0][j] = t0 ? l[0][j + 1] : l[0][j];
      l[1][j] = t1 ? l[1][j + 1] : l[1][j];
      l[2][j] = t2 ? l[2][j + 1] : l[2][j];
      l[3][j] = t3 ? l[3][j + 1] : l[3][j];
    }
    l[0][8] = t0 ? BIGF : l[0][8];
    l[1][8] = t1 ? BIGF : l[1][8];
    l[2][8] = t2 ? BIGF : l[2][8];
    l[3][8] = t3 ? BIGF : l[3][8];
  }
}

extern "C" void kernel_launch(void* const* d_in, const int* in_sizes, int n_in,
                              void* d_out, int out_size, void* d_ws, size_t ws_size,
                              hipStream_t stream) {
  const float* emb = (const float*)d_in[0];
  const float* mem = (const float*)d_in[1];
  float* out = (float*)d_out;
  char* ws = (char*)d_ws;
  size_t offA = 0;
  size_t offB = offA + (size_t)N_ROWS * D_DIM * 2;   // A bf16: 25,165,824
  size_t offX = offB + (size_t)M_ROWS * D_DIM * 2;   // B bf16: +6,291,456
  size_t offY = offX + (size_t)N_ROWS * 4;           // +131,072
  size_t offP = offY + (size_t)M_ROWS * 4;           // +32,768
  // partials: 4 quarters x N x 9 f32 = 4,718,592  (total ~36.3 MB)
  __hip_bfloat16* Ab = (__hip_bfloat16*)(ws + offA);
  __hip_bfloat16* Bb = (__hip_bfloat16*)(ws + offB);
  float* xn = (float*)(ws + offX);
  float* yn = (float*)(ws + offY);
  float* part = (float*)(ws + offP);

  FAPM_prep<<<(N_ROWS + M_ROWS) / 4, 256, 0, stream>>>(emb, mem, Ab, Bb, xn, yn);
  FAPM_fused<<<(N_ROWS / 128) * 4, 256, 0, stream>>>(Ab, Bb, xn, yn, part);
  FAPM_merge4<<<N_ROWS / 256, 256, 0, stream>>>(part, out);
}

// Round 4
// 239.670 us; speedup vs baseline: 1.2118x; 1.2118x over previous
//
#include <hip/hip_runtime.h>
#include <hip/hip_bf16.h>

#define N_ROWS 32768
#define M_ROWS 8192
#define D_DIM  384
#define K_NB   9
#define BN     64
#define MHALF  (M_ROWS / 2)      // 4096 cols per block
#define TILES  (MHALF / BN)      // 64
#define KP     6                 // K pair-steps (384 / 64)

#define QRANGE 2048.0f
#define QSCALE (1.0f / 2048.0f)
#define QSTEPF (QRANGE / 65535.0f)
#define M2S    (-2.0f * QSCALE)
#define BIGF   3.0e38f

typedef long i64;
typedef __attribute__((ext_vector_type(2))) long i64x2;
typedef __attribute__((ext_vector_type(4))) float f32x4;
typedef __attribute__((ext_vector_type(2))) unsigned short u16x2;

// ---- prep: f32 -> permuted fp8(e4m3) rows + exact f32 norms ----
// Permutation sigma per 384-elem row: byte position p = kp*64 + grp*16 + half*8 + j
// holds element k = kp*64 + half*32 + grp*8 + j. Then a 16B chunk at
// (kp*64 + grp*16) is lane (sub,grp)'s fragments for kk=2kp and 2kp+1.
__global__ __launch_bounds__(256) void FAPM_prep8(
    const float* __restrict__ emb, const float* __restrict__ mem,
    unsigned* __restrict__ A8, unsigned* __restrict__ B8,
    float* __restrict__ xn, float* __restrict__ yn) {
  const int lane = threadIdx.x & 63;
  const int row  = blockIdx.x * 4 + (threadIdx.x >> 6);
  const float* src;
  unsigned* dst;
  float* nptr;
  if (row < N_ROWS) {
    src = emb + (size_t)row * D_DIM; dst = A8 + (size_t)row * 96; nptr = xn + row;
  } else {
    int r = row - N_ROWS;
    src = mem + (size_t)r * D_DIM; dst = B8 + (size_t)r * 96; nptr = yn + r;
  }
  float s = 0.f;
  // output dword dw -> input float4 at k0(dw)
  {
    int dw = lane;  // 0..63
    int kp = dw >> 4, r4 = dw & 15;
    int grp = r4 >> 2, half = (r4 >> 1) & 1, j = (r4 & 1) * 4;
    int k0 = kp * 64 + half * 32 + grp * 8 + j;
    f32x4 v = *(const f32x4*)(src + k0);
    s += v.x * v.x + v.y * v.y + v.z * v.z + v.w * v.w;
    int pk = __builtin_amdgcn_cvt_pk_fp8_f32(v.x, v.y, 0, false);
    pk = __builtin_amdgcn_cvt_pk_fp8_f32(v.z, v.w, pk, true);
    dst[dw] = (unsigned)pk;
  }
  if (lane < 32) {
    int dw = lane + 64;  // 64..95
    int kp = dw >> 4, r4 = dw & 15;
    int grp = r4 >> 2, half = (r4 >> 1) & 1, j = (r4 & 1) * 4;
    int k0 = kp * 64 + half * 32 + grp * 8 + j;
    f32x4 v = *(const f32x4*)(src + k0);
    s += v.x * v.x + v.y * v.y + v.z * v.z + v.w * v.w;
    int pk = __builtin_amdgcn_cvt_pk_fp8_f32(v.x, v.y, 0, false);
    pk = __builtin_amdgcn_cvt_pk_fp8_f32(v.z, v.w, pk, true);
    dst[dw] = (unsigned)pk;
  }
#pragma unroll
  for (int dd = 1; dd < 64; dd <<= 1) s += __shfl_xor(s, dd);
  if (lane == 0) *nptr = s;
}

// ---- 16-lane merge of per-lane sorted u16 lists; writes f32 d^2 ascending ----
__device__ __forceinline__ void merge16i(unsigned t[9], float* dst, int sub) {
  for (int s = 0; s < K_NB; ++s) {
    unsigned m  = t[0];
    int      ml = sub;
#pragma unroll
    for (int dd = 1; dd < 16; dd <<= 1) {
      unsigned ov = (unsigned)__shfl_xor((int)m, dd);
      int      ol = __shfl_xor(ml, dd);
      bool take = (ov < m) || (ov == m && ol < ml);
      m  = take ? ov : m;
      ml = take ? ol : ml;
    }
    if (sub == ml) {
#pragma unroll
      for (int j = 0; j < 8; ++j) t[j] = t[j + 1];
      t[8] = 0xFFFFu;
    }
    if (sub == 0) dst[s] = (float)m * QSTEPF;
  }
}

// ------- fused: fp8 MFMA d^2 + packed-u16 top-9, half of M -------
__global__ __launch_bounds__(256, 2) void FAPM_fused(
    const unsigned char* __restrict__ A8, const unsigned char* __restrict__ B8,
    const float* __restrict__ xn, const float* __restrict__ yn,
    float* __restrict__ part) {
  // B tile 64 rows x 384 k fp8 as 24 contiguous 1KB subtiles [cb*6+kp];
  // lane l reads its 16B (fragments kk=2kp,2kp+1) at l*16: conflict-free.
  __shared__ __attribute__((aligned(128))) unsigned char Bs[24 * 1024];
  const int tid  = threadIdx.x;
  const int lane = tid & 63;
  const int w    = tid >> 6;          // wave 0..3
  const int sub  = lane & 15;
  const int grp  = lane >> 4;
  const int bx   = blockIdx.x;
  const int mh   = bx & 1;            // which M-half
  const int wrow0 = (bx >> 1) * 128 + w * 32;  // wave owns 32 rows
  const int colbase = mh * MHALF;

  // A fragments (fp8): 2 row-blocks of 16, 12 K-steps, 1 i64 each
  i64 af0[12], af1[12];
  {
    const unsigned char* ap0 = A8 + (size_t)(wrow0 + sub) * D_DIM + grp * 16;
    const unsigned char* ap1 = ap0 + 16 * D_DIM;
#pragma unroll
    for (int kp = 0; kp < KP; ++kp) {
      i64x2 v0 = *(const i64x2*)(ap0 + kp * 64);
      i64x2 v1 = *(const i64x2*)(ap1 + kp * 64);
      af0[2 * kp] = v0.x; af0[2 * kp + 1] = v0.y;
      af1[2 * kp] = v1.x; af1[2 * kp + 1] = v1.y;
    }
  }
  float xs0[4], xs1[4];
#pragma unroll
  for (int i = 0; i < 4; ++i) {
    xs0[i] = xn[wrow0 + grp * 4 + i] * QSCALE;
    xs1[i] = xn[wrow0 + 16 + grp * 4 + i] * QSCALE;
  }

  u16x2 tkp[4][9];  // packed (rowblock0, rowblock1) top-9, quantized d^2
#pragma unroll
  for (int i = 0; i < 4; ++i)
#pragma unroll
    for (int j = 0; j < 9; ++j) { tkp[i][j].x = 0xFFFFu; tkp[i][j].y = 0xFFFFu; }

  const unsigned char* bread = Bs + lane * 16;
  const int s_row = lane & 15;
  const int s_off = (lane >> 4) * 16;

  for (int t = 0; t < TILES; ++t) {
    const int col0 = colbase + t * BN;
    // wave w stages cb=w: rows col0+w*16+s_row, 6 chunks of 64B apart
    const unsigned char* bsrc =
        B8 + (size_t)(col0 + w * 16 + s_row) * D_DIM + s_off;
#pragma unroll
    for (int q = 0; q < KP; ++q) {
      __builtin_amdgcn_global_load_lds(
          (const __attribute__((address_space(1))) void*)(bsrc + q * 64),
          (__attribute__((address_space(3))) void*)(Bs + (w * KP + q) * 1024),
          16, 0, 0);
    }
    float ysv[4];
#pragma unroll
    for (int cb = 0; cb < 4; ++cb) ysv[cb] = yn[col0 + cb * 16 + sub] * QSCALE;
    asm volatile("s_waitcnt vmcnt(0)" ::: "memory");
    __syncthreads();

#pragma unroll
    for (int cb = 0; cb < 4; ++cb) {
      f32x4 acc0 = {0.f, 0.f, 0.f, 0.f}, acc1 = {0.f, 0.f, 0.f, 0.f};
#pragma unroll
      for (int kp = 0; kp < KP; ++kp) {
        i64x2 b = *(const i64x2*)(bread + (cb * KP + kp) * 1024);
        acc0 = __builtin_amdgcn_mfma_f32_16x16x32_fp8_fp8(af0[2 * kp], b.x, acc0, 0, 0, 0);
        acc1 = __builtin_amdgcn_mfma_f32_16x16x32_fp8_fp8(af1[2 * kp], b.x, acc1, 0, 0, 0);
        acc0 = __builtin_amdgcn_mfma_f32_16x16x32_fp8_fp8(af0[2 * kp + 1], b.y, acc0, 0, 0, 0);
        acc1 = __builtin_amdgcn_mfma_f32_16x16x32_fp8_fp8(af1[2 * kp + 1], b.y, acc1, 0, 0, 0);
      }
#pragma unroll
      for (int i = 0; i < 4; ++i) {
        float d2a = fmaf(acc0[i], M2S, xs0[i] + ysv[cb]);
        float d2b = fmaf(acc1[i], M2S, xs1[i] + ysv[cb]);
        unsigned dpu;
        asm("v_cvt_pknorm_u16_f32 %0, %1, %2" : "=v"(dpu) : "v"(d2a), "v"(d2b));
        u16x2 dp = __builtin_bit_cast(u16x2, dpu);
#pragma unroll
        for (int j = 8; j >= 1; --j)
          tkp[i][j] = __builtin_elementwise_min(
              tkp[i][j], __builtin_elementwise_max(dp, tkp[i][j - 1]));
        tkp[i][0] = __builtin_elementwise_min(tkp[i][0], dp);
      }
    }
    __syncthreads();
  }

  // ---- unpack + per-row merge across 16 sub-lanes; write f32 d^2 partials ----
  float* pbase = part + (size_t)mh * N_ROWS * K_NB;
#pragma unroll
  for (int i = 0; i < 4; ++i) {
    unsigned ta[9], tb[9];
#pragma unroll
    for (int j = 0; j < 9; ++j) { ta[j] = tkp[i][j].x; tb[j] = tkp[i][j].y; }
    merge16i(ta, pbase + (size_t)(wrow0 + grp * 4 + i) * K_NB, sub);
    merge16i(tb, pbase + (size_t)(wrow0 + 16 + grp * 4 + i) * K_NB, sub);
  }
}

// ------- merge the two M-half partials, sqrt, final output -------
__global__ __launch_bounds__(256) void FAPM_merge(
    const float* __restrict__ part, float* __restrict__ out) {
  const int r = blockIdx.x * 256 + threadIdx.x;
  const float* pa = part + (size_t)r * K_NB;
  const float* pb = part + (size_t)N_ROWS * K_NB + (size_t)r * K_NB;
  float a[9], b[9];
#pragma unroll
  for (int j = 0; j < 9; ++j) { a[j] = pa[j]; b[j] = pb[j]; }
#pragma unroll
  for (int s = 0; s < K_NB; ++s) {
    bool ta = a[0] <= b[0];
    float m = ta ? a[0] : b[0];
    out[(size_t)r * K_NB + s] = sqrtf(fmaxf(m, 0.f));
#pragma unroll
    for (int j = 0; j < 8; ++j) {
      float an = a[j + 1], bn = b[j + 1];
      a[j] = ta ? an : a[j];
      b[j] = ta ? b[j] : bn;
    }
    a[8] = ta ? BIGF : a[8];
    b[8] = ta ? b[8] : BIGF;
  }
}

extern "C" void kernel_launch(void* const* d_in, const int* in_sizes, int n_in,
                              void* d_out, int out_size, void* d_ws, size_t ws_size,
                              hipStream_t stream) {
  const float* emb = (const float*)d_in[0];
  const float* mem = (const float*)d_in[1];
  float* out = (float*)d_out;
  char* ws = (char*)d_ws;
  size_t offA = 0;
  size_t offB = offA + (size_t)N_ROWS * D_DIM;       // A8: 12,582,912
  size_t offX = offB + (size_t)M_ROWS * D_DIM;       // B8: +3,145,728
  size_t offY = offX + (size_t)N_ROWS * 4;           // +131,072
  size_t offP = offY + (size_t)M_ROWS * 4;           // +32,768
  // partials: 2 halves x N x 9 f32 = 2,359,296  (total ~18.3 MB)
  unsigned char* A8 = (unsigned char*)(ws + offA);
  unsigned char* B8 = (unsigned char*)(ws + offB);
  float* xn = (float*)(ws + offX);
  float* yn = (float*)(ws + offY);
  float* part = (float*)(ws + offP);

  FAPM_prep8<<<(N_ROWS + M_ROWS) / 4, 256, 0, stream>>>(
      emb, mem, (unsigned*)A8, (unsigned*)B8, xn, yn);
  FAPM_fused<<<(N_ROWS / 128) * 2, 256, 0, stream>>>(A8, B8, xn, yn, part);
  FAPM_merge<<<N_ROWS / 256, 256, 0, stream>>>(part, out);
}

// Round 5
// 225.072 us; speedup vs baseline: 1.2904x; 1.0649x over previous
//
#include <hip/hip_runtime.h>
#include <hip/hip_bf16.h>

#define N_ROWS 32768
#define M_ROWS 8192
#define D_DIM  384
#define K_NB   9
#define BN     64
#define MHALF  (M_ROWS / 2)      // 4096 cols per block
#define TILES  (MHALF / BN)      // 64
#define KP     6                 // K pair-steps (384 / 64)

#define QRANGE 2048.0f
#define QSCALE (1.0f / 2048.0f)
#define QSTEPF (QRANGE / 65535.0f)
#define M2S    (-2.0f * QSCALE)
#define BIGF   3.0e38f

typedef long i64;
typedef __attribute__((ext_vector_type(2))) long i64x2;
typedef __attribute__((ext_vector_type(4))) float f32x4;
typedef __attribute__((ext_vector_type(2))) unsigned short u16x2;

// ---- prep: f32 -> permuted fp8(e4m3) rows + exact f32 norms ----
// Permutation sigma per 384-elem row: byte position p = kp*64 + grp*16 + half*8 + j
// holds element k = kp*64 + half*32 + grp*8 + j. Then a 16B chunk at
// (kp*64 + grp*16) is lane (sub,grp)'s fragments for kk=2kp and 2kp+1.
__global__ __launch_bounds__(256) void FAPM_prep8(
    const float* __restrict__ emb, const float* __restrict__ mem,
    unsigned* __restrict__ A8, unsigned* __restrict__ B8,
    float* __restrict__ xn, float* __restrict__ yn) {
  const int lane = threadIdx.x & 63;
  const int row  = blockIdx.x * 4 + (threadIdx.x >> 6);
  const float* src;
  unsigned* dst;
  float* nptr;
  if (row < N_ROWS) {
    src = emb + (size_t)row * D_DIM; dst = A8 + (size_t)row * 96; nptr = xn + row;
  } else {
    int r = row - N_ROWS;
    src = mem + (size_t)r * D_DIM; dst = B8 + (size_t)r * 96; nptr = yn + r;
  }
  float s = 0.f;
  {
    int dw = lane;  // 0..63
    int kp = dw >> 4, r4 = dw & 15;
    int grp = r4 >> 2, half = (r4 >> 1) & 1, j = (r4 & 1) * 4;
    int k0 = kp * 64 + half * 32 + grp * 8 + j;
    f32x4 v = *(const f32x4*)(src + k0);
    s += v.x * v.x + v.y * v.y + v.z * v.z + v.w * v.w;
    int pk = __builtin_amdgcn_cvt_pk_fp8_f32(v.x, v.y, 0, false);
    pk = __builtin_amdgcn_cvt_pk_fp8_f32(v.z, v.w, pk, true);
    dst[dw] = (unsigned)pk;
  }
  if (lane < 32) {
    int dw = lane + 64;  // 64..95
    int kp = dw >> 4, r4 = dw & 15;
    int grp = r4 >> 2, half = (r4 >> 1) & 1, j = (r4 & 1) * 4;
    int k0 = kp * 64 + half * 32 + grp * 8 + j;
    f32x4 v = *(const f32x4*)(src + k0);
    s += v.x * v.x + v.y * v.y + v.z * v.z + v.w * v.w;
    int pk = __builtin_amdgcn_cvt_pk_fp8_f32(v.x, v.y, 0, false);
    pk = __builtin_amdgcn_cvt_pk_fp8_f32(v.z, v.w, pk, true);
    dst[dw] = (unsigned)pk;
  }
#pragma unroll
  for (int dd = 1; dd < 64; dd <<= 1) s += __shfl_xor(s, dd);
  if (lane == 0) *nptr = s;
}

// ---- 16-lane merge of per-lane sorted u16 lists; writes f32 d^2 ascending ----
__device__ __forceinline__ void merge16i(unsigned t[9], float* dst, int sub) {
  for (int s = 0; s < K_NB; ++s) {
    unsigned m  = t[0];
    int      ml = sub;
#pragma unroll
    for (int dd = 1; dd < 16; dd <<= 1) {
      unsigned ov = (unsigned)__shfl_xor((int)m, dd);
      int      ol = __shfl_xor(ml, dd);
      bool take = (ov < m) || (ov == m && ol < ml);
      m  = take ? ov : m;
      ml = take ? ol : ml;
    }
    if (sub == ml) {
#pragma unroll
      for (int j = 0; j < 8; ++j) t[j] = t[j + 1];
      t[8] = 0xFFFFu;
    }
    if (sub == 0) dst[s] = (float)m * QSTEPF;
  }
}

// ------- fused: A+B in LDS, kp-outer 8-acc fp8 MFMA + packed-u16 top-9 -------
__global__ __launch_bounds__(256, 2) void FAPM_fused(
    const unsigned char* __restrict__ A8, const unsigned char* __restrict__ B8,
    const float* __restrict__ xn, const float* __restrict__ yn,
    float* __restrict__ part) {
  // A tile: 128 rows x 384 fp8 as 48 x 1KB subtiles [(w*2+rb)*6+kp], staged once.
  // B tile:  64 rows x 384 fp8 as 24 x 1KB subtiles [cb*6+kp], staged per tile.
  // Within a subtile, lane l's 16B (fragments kk=2kp,2kp+1 of row l&15) is at l*16.
  __shared__ __attribute__((aligned(128))) unsigned char As[48 * 1024];
  __shared__ __attribute__((aligned(128))) unsigned char Bs[24 * 1024];
  const int tid  = threadIdx.x;
  const int lane = tid & 63;
  const int w    = tid >> 6;          // wave 0..3
  const int sub  = lane & 15;
  const int grp  = lane >> 4;
  const int bx   = blockIdx.x;
  const int mh   = bx & 1;            // which M-half
  const int wrow0 = (bx >> 1) * 128 + w * 32;  // wave owns 32 rows
  const int colbase = mh * MHALF;

  // ---- stage A once: wave w fills its 12 subtiles (rb,kp) ----
  {
    const unsigned char* asrc = A8 + (size_t)(wrow0 + sub) * D_DIM + grp * 16;
#pragma unroll
    for (int rb = 0; rb < 2; ++rb)
#pragma unroll
      for (int q = 0; q < KP; ++q)
        __builtin_amdgcn_global_load_lds(
            (const __attribute__((address_space(1))) void*)(asrc + rb * 16 * D_DIM + q * 64),
            (__attribute__((address_space(3))) void*)(As + ((w * 2 + rb) * KP + q) * 1024),
            16, 0, 0);
  }
  // ---- stage B tile 0: wave w fills subtiles cb=w ----
  {
    const unsigned char* bsrc =
        B8 + (size_t)(colbase + w * 16 + sub) * D_DIM + grp * 16;
#pragma unroll
    for (int q = 0; q < KP; ++q)
      __builtin_amdgcn_global_load_lds(
          (const __attribute__((address_space(1))) void*)(bsrc + q * 64),
          (__attribute__((address_space(3))) void*)(Bs + (w * KP + q) * 1024),
          16, 0, 0);
  }

  float xs0[4], xs1[4];
#pragma unroll
  for (int i = 0; i < 4; ++i) {
    xs0[i] = xn[wrow0 + grp * 4 + i] * QSCALE;
    xs1[i] = xn[wrow0 + 16 + grp * 4 + i] * QSCALE;
  }

  u16x2 tkp[4][9];  // packed (rowblock0, rowblock1) top-9, quantized d^2
#pragma unroll
  for (int i = 0; i < 4; ++i)
#pragma unroll
    for (int j = 0; j < 9; ++j) { tkp[i][j].x = 0xFFFFu; tkp[i][j].y = 0xFFFFu; }

  const unsigned char* ar0 = As + (w * 2 + 0) * KP * 1024 + lane * 16;
  const unsigned char* ar1 = As + (w * 2 + 1) * KP * 1024 + lane * 16;
  const unsigned char* br  = Bs + lane * 16;

  asm volatile("s_waitcnt vmcnt(0)" ::: "memory");
  __syncthreads();

  for (int t = 0; t < TILES; ++t) {
    const int col0 = colbase + t * BN;
    // y-norms for this tile, issued early (consumed in topk after stage-issue)
    float ysv[4];
#pragma unroll
    for (int cb = 0; cb < 4; ++cb) ysv[cb] = yn[col0 + cb * 16 + sub] * QSCALE;

    f32x4 acc[2][4];
#pragma unroll
    for (int rb = 0; rb < 2; ++rb)
#pragma unroll
      for (int cb = 0; cb < 4; ++cb) acc[rb][cb] = (f32x4){0.f, 0.f, 0.f, 0.f};

    __builtin_amdgcn_s_setprio(1);
#pragma unroll
    for (int kp = 0; kp < KP; ++kp) {
      i64x2 a0 = *(const i64x2*)(ar0 + kp * 1024);
      i64x2 a1 = *(const i64x2*)(ar1 + kp * 1024);
#pragma unroll
      for (int cb = 0; cb < 4; ++cb) {
        i64x2 b = *(const i64x2*)(br + (cb * KP + kp) * 1024);
        acc[0][cb] = __builtin_amdgcn_mfma_f32_16x16x32_fp8_fp8(a0.x, b.x, acc[0][cb], 0, 0, 0);
        acc[1][cb] = __builtin_amdgcn_mfma_f32_16x16x32_fp8_fp8(a1.x, b.x, acc[1][cb], 0, 0, 0);
        acc[0][cb] = __builtin_amdgcn_mfma_f32_16x16x32_fp8_fp8(a0.y, b.y, acc[0][cb], 0, 0, 0);
        acc[1][cb] = __builtin_amdgcn_mfma_f32_16x16x32_fp8_fp8(a1.y, b.y, acc[1][cb], 0, 0, 0);
      }
    }
    __builtin_amdgcn_s_setprio(0);
    __syncthreads();  // all waves finished reading Bs for tile t

    // issue next B-stage now; its latency hides under the topk VALU tail
    if (t + 1 < TILES) {
      const unsigned char* bsrc =
          B8 + (size_t)(col0 + BN + w * 16 + sub) * D_DIM + grp * 16;
#pragma unroll
      for (int q = 0; q < KP; ++q)
        __builtin_amdgcn_global_load_lds(
            (const __attribute__((address_space(1))) void*)(bsrc + q * 64),
            (__attribute__((address_space(3))) void*)(Bs + (w * KP + q) * 1024),
            16, 0, 0);
    }

    // ---- topk update (VALU only, no LDS) ----
#pragma unroll
    for (int cb = 0; cb < 4; ++cb) {
#pragma unroll
      for (int i = 0; i < 4; ++i) {
        float d2a = fmaf(acc[0][cb][i], M2S, xs0[i] + ysv[cb]);
        float d2b = fmaf(acc[1][cb][i], M2S, xs1[i] + ysv[cb]);
        unsigned dpu;
        asm("v_cvt_pknorm_u16_f32 %0, %1, %2" : "=v"(dpu) : "v"(d2a), "v"(d2b));
        u16x2 dp = __builtin_bit_cast(u16x2, dpu);
#pragma unroll
        for (int j = 8; j >= 1; --j)
          tkp[i][j] = __builtin_elementwise_min(
              tkp[i][j], __builtin_elementwise_max(dp, tkp[i][j - 1]));
        tkp[i][0] = __builtin_elementwise_min(tkp[i][0], dp);
      }
    }

    asm volatile("s_waitcnt vmcnt(0)" ::: "memory");
    __syncthreads();
  }

  // ---- unpack + per-row merge across 16 sub-lanes; write f32 d^2 partials ----
  float* pbase = part + (size_t)mh * N_ROWS * K_NB;
#pragma unroll
  for (int i = 0; i < 4; ++i) {
    unsigned ta[9], tb[9];
#pragma unroll
    for (int j = 0; j < 9; ++j) { ta[j] = tkp[i][j].x; tb[j] = tkp[i][j].y; }
    merge16i(ta, pbase + (size_t)(wrow0 + grp * 4 + i) * K_NB, sub);
    merge16i(tb, pbase + (size_t)(wrow0 + 16 + grp * 4 + i) * K_NB, sub);
  }
}

// ------- merge the two M-half partials, sqrt, final output -------
__global__ __launch_bounds__(256) void FAPM_merge(
    const float* __restrict__ part, float* __restrict__ out) {
  const int r = blockIdx.x * 256 + threadIdx.x;
  const float* pa = part + (size_t)r * K_NB;
  const float* pb = part + (size_t)N_ROWS * K_NB + (size_t)r * K_NB;
  float a[9], b[9];
#pragma unroll
  for (int j = 0; j < 9; ++j) { a[j] = pa[j]; b[j] = pb[j]; }
#pragma unroll
  for (int s = 0; s < K_NB; ++s) {
    bool ta = a[0] <= b[0];
    float m = ta ? a[0] : b[0];
    out[(size_t)r * K_NB + s] = sqrtf(fmaxf(m, 0.f));
#pragma unroll
    for (int j = 0; j < 8; ++j) {
      float an = a[j + 1], bn = b[j + 1];
      a[j] = ta ? an : a[j];
      b[j] = ta ? b[j] : bn;
    }
    a[8] = ta ? BIGF : a[8];
    b[8] = ta ? b[8] : BIGF;
  }
}

extern "C" void kernel_launch(void* const* d_in, const int* in_sizes, int n_in,
                              void* d_out, int out_size, void* d_ws, size_t ws_size,
                              hipStream_t stream) {
  const float* emb = (const float*)d_in[0];
  const float* mem = (const float*)d_in[1];
  float* out = (float*)d_out;
  char* ws = (char*)d_ws;
  size_t offA = 0;
  size_t offB = offA + (size_t)N_ROWS * D_DIM;       // A8: 12,582,912
  size_t offX = offB + (size_t)M_ROWS * D_DIM;       // B8: +3,145,728
  size_t offY = offX + (size_t)N_ROWS * 4;           // +131,072
  size_t offP = offY + (size_t)M_ROWS * 4;           // +32,768
  // partials: 2 halves x N x 9 f32 = 2,359,296  (total ~18.3 MB)
  unsigned char* A8 = (unsigned char*)(ws + offA);
  unsigned char* B8 = (unsigned char*)(ws + offB);
  float* xn = (float*)(ws + offX);
  float* yn = (float*)(ws + offY);
  float* part = (float*)(ws + offP);

  FAPM_prep8<<<(N_ROWS + M_ROWS) / 4, 256, 0, stream>>>(
      emb, mem, (unsigned*)A8, (unsigned*)B8, xn, yn);
  FAPM_fused<<<(N_ROWS / 128) * 2, 256, 0, stream>>>(A8, B8, xn, yn, part);
  FAPM_merge<<<N_ROWS / 256, 256, 0, stream>>>(part, out);
}

// Round 6
// 210.591 us; speedup vs baseline: 1.3791x; 1.0688x over previous
//
#include <hip/hip_runtime.h>
#include <hip/hip_bf16.h>

#define N_ROWS 32768
#define M_ROWS 8192
#define D_DIM  384
#define K_NB   9
#define BN     64
#define MQ     (M_ROWS / 4)      // 2048 cols per block
#define TILES  (MQ / BN)         // 32
#define KP     6                 // K pair-steps (384 / 64)

#define QRANGE 2048.0f
#define QSCALE (1.0f / 2048.0f)
#define QSTEPF (QRANGE / 65535.0f)
#define M2S    (-2.0f * QSCALE)
#define BIGF   3.0e38f

#define YS_OFF 49152             // LDS byte offset of Ys region

typedef long i64;
typedef __attribute__((ext_vector_type(2))) long i64x2;
typedef __attribute__((ext_vector_type(4))) float f32x4;
typedef __attribute__((ext_vector_type(4))) unsigned u32x4;
typedef __attribute__((ext_vector_type(2))) unsigned short u16x2;

// ---- prep: f32 -> permuted fp8(e4m3) rows + exact f32 norms ----
// sigma per 384-elem row: byte p = kp*64 + grp*16 + half*8 + j  holds
// element k = kp*64 + half*32 + grp*8 + j  ->  16B chunk at (kp*64+grp*16)
// is lane (sub,grp)'s fragments for kk=2kp,2kp+1.
__global__ __launch_bounds__(256) void FAPM_prep8(
    const float* __restrict__ emb, const float* __restrict__ mem,
    unsigned* __restrict__ A8, unsigned* __restrict__ B8,
    float* __restrict__ xn, float* __restrict__ yn) {
  const int lane = threadIdx.x & 63;
  const int row  = blockIdx.x * 4 + (threadIdx.x >> 6);
  const float* src;
  unsigned* dst;
  float* nptr;
  if (row < N_ROWS) {
    src = emb + (size_t)row * D_DIM; dst = A8 + (size_t)row * 96; nptr = xn + row;
  } else {
    int r = row - N_ROWS;
    src = mem + (size_t)r * D_DIM; dst = B8 + (size_t)r * 96; nptr = yn + r;
  }
  float s = 0.f;
  {
    int dw = lane;
    int kp = dw >> 4, r4 = dw & 15;
    int grp = r4 >> 2, half = (r4 >> 1) & 1, j = (r4 & 1) * 4;
    int k0 = kp * 64 + half * 32 + grp * 8 + j;
    f32x4 v = *(const f32x4*)(src + k0);
    s += v.x * v.x + v.y * v.y + v.z * v.z + v.w * v.w;
    int pk = __builtin_amdgcn_cvt_pk_fp8_f32(v.x, v.y, 0, false);
    pk = __builtin_amdgcn_cvt_pk_fp8_f32(v.z, v.w, pk, true);
    dst[dw] = (unsigned)pk;
  }
  if (lane < 32) {
    int dw = lane + 64;
    int kp = dw >> 4, r4 = dw & 15;
    int grp = r4 >> 2, half = (r4 >> 1) & 1, j = (r4 & 1) * 4;
    int k0 = kp * 64 + half * 32 + grp * 8 + j;
    f32x4 v = *(const f32x4*)(src + k0);
    s += v.x * v.x + v.y * v.y + v.z * v.z + v.w * v.w;
    int pk = __builtin_amdgcn_cvt_pk_fp8_f32(v.x, v.y, 0, false);
    pk = __builtin_amdgcn_cvt_pk_fp8_f32(v.z, v.w, pk, true);
    dst[dw] = (unsigned)pk;
  }
#pragma unroll
  for (int dd = 1; dd < 64; dd <<= 1) s += __shfl_xor(s, dd);
  if (lane == 0) *nptr = s;
}

// ---- 16-lane merge of per-lane sorted u16 lists; writes f32 d^2 ascending ----
__device__ __forceinline__ void merge16i(unsigned t[9], float* dst, int sub) {
  for (int s = 0; s < K_NB; ++s) {
    unsigned m  = t[0];
    int      ml = sub;
#pragma unroll
    for (int dd = 1; dd < 16; dd <<= 1) {
      unsigned ov = (unsigned)__shfl_xor((int)m, dd);
      int      ol = __shfl_xor(ml, dd);
      bool take = (ov < m) || (ov == m && ol < ml);
      m  = take ? ov : m;
      ml = take ? ol : ml;
    }
    if (sub == ml) {
#pragma unroll
      for (int j = 0; j < 8; ++j) t[j] = t[j + 1];
      t[8] = 0xFFFFu;
    }
    if (sub == 0) dst[s] = (float)m * QSTEPF;
  }
}

// ------- fused: A->regs via LDS, B double-buffered, counted vmcnt -------
__global__ __launch_bounds__(256, 3) void FAPM_fused(
    const unsigned char* __restrict__ A8, const unsigned char* __restrict__ B8,
    const float* __restrict__ xn, const float* __restrict__ yn,
    float* __restrict__ part) {
  // [0,48K): A stage (prologue), then B buf0 [0,24K) / buf1 [24K,48K)
  // [48K,52K): Ys as unorm16 (2048 entries)
  __shared__ __attribute__((aligned(128))) unsigned char LDS[53248];
  const int tid  = threadIdx.x;
  const int lane = tid & 63;
  const int w    = tid >> 6;
  const int sub  = lane & 15;
  const int grp  = lane >> 4;
  const int bx   = blockIdx.x;
  const int mq   = bx & 3;
  const int wrow0 = (bx >> 2) * 128 + w * 32;
  const int colbase = mq * MQ;

  // x-norms (pre-scaled) — loaded before any staging
  float xs0[4], xs1[4];
#pragma unroll
  for (int i = 0; i < 4; ++i) {
    xs0[i] = xn[wrow0 + grp * 4 + i] * QSCALE;
    xs1[i] = xn[wrow0 + 16 + grp * 4 + i] * QSCALE;
  }

  // ---- Ys region: 8 y-norms per thread -> unorm16 ----
  {
    const float* yp = yn + colbase + tid * 8;
    f32x4 v0 = *(const f32x4*)yp;
    f32x4 v1 = *(const f32x4*)(yp + 4);
    float a0 = v0.x * QSCALE, a1 = v0.y * QSCALE, a2 = v0.z * QSCALE, a3 = v0.w * QSCALE;
    float a4 = v1.x * QSCALE, a5 = v1.y * QSCALE, a6 = v1.z * QSCALE, a7 = v1.w * QSCALE;
    unsigned q0, q1, q2, q3;
    asm("v_cvt_pknorm_u16_f32 %0, %1, %2" : "=v"(q0) : "v"(a0), "v"(a1));
    asm("v_cvt_pknorm_u16_f32 %0, %1, %2" : "=v"(q1) : "v"(a2), "v"(a3));
    asm("v_cvt_pknorm_u16_f32 %0, %1, %2" : "=v"(q2) : "v"(a4), "v"(a5));
    asm("v_cvt_pknorm_u16_f32 %0, %1, %2" : "=v"(q3) : "v"(a6), "v"(a7));
    *(u32x4*)(&LDS[YS_OFF + tid * 16]) = (u32x4){q0, q1, q2, q3};
  }

  // ---- stage A (once): wave w fills its 12 subtiles ----
  {
    const unsigned char* asrc = A8 + (size_t)(wrow0 + sub) * D_DIM + grp * 16;
#pragma unroll
    for (int rb = 0; rb < 2; ++rb)
#pragma unroll
      for (int q = 0; q < KP; ++q)
        __builtin_amdgcn_global_load_lds(
            (const __attribute__((address_space(1))) void*)(asrc + rb * 16 * D_DIM + q * 64),
            (__attribute__((address_space(3))) void*)(LDS + ((w * 2 + rb) * KP + q) * 1024),
            16, 0, 0);
  }
  asm volatile("s_waitcnt vmcnt(0)" ::: "memory");
  __syncthreads();

  // ---- A LDS -> registers (forced resident: LDS below is rewritten) ----
  i64 af0[12], af1[12];
  {
    const unsigned char* ar0 = LDS + (w * 2) * (KP * 1024) + lane * 16;
    const unsigned char* ar1 = ar0 + KP * 1024;
#pragma unroll
    for (int kp = 0; kp < KP; ++kp) {
      i64x2 v0 = *(const i64x2*)(ar0 + kp * 1024);
      i64x2 v1 = *(const i64x2*)(ar1 + kp * 1024);
      af0[2 * kp] = v0.x; af0[2 * kp + 1] = v0.y;
      af1[2 * kp] = v1.x; af1[2 * kp + 1] = v1.y;
    }
  }
  __syncthreads();  // all waves done reading A region; reuse as B buffers

  // ---- prime the 2-deep B pipeline ----
  const unsigned char* bsrc = B8 + (size_t)(colbase + w * 16 + sub) * D_DIM + grp * 16;
#pragma unroll
  for (int q = 0; q < KP; ++q)
    __builtin_amdgcn_global_load_lds(
        (const __attribute__((address_space(1))) void*)(bsrc + q * 64),
        (__attribute__((address_space(3))) void*)(LDS + (w * KP + q) * 1024),
        16, 0, 0);
#pragma unroll
  for (int q = 0; q < KP; ++q)
    __builtin_amdgcn_global_load_lds(
        (const __attribute__((address_space(1))) void*)(bsrc + 24576 + q * 64),
        (__attribute__((address_space(3))) void*)(LDS + 24576 + (w * KP + q) * 1024),
        16, 0, 0);
  bsrc += 2 * 24576;

  u16x2 tkp[4][9];
#pragma unroll
  for (int i = 0; i < 4; ++i)
#pragma unroll
    for (int j = 0; j < 9; ++j) { tkp[i][j].x = 0xFFFFu; tkp[i][j].y = 0xFFFFu; }

  for (int t = 0; t < TILES; ++t) {
    const int bufo = (t & 1) * 24576;
    // wait for OUR stage(t) (6 newer loads may stay in flight), then publish
    if (t + 1 < TILES) asm volatile("s_waitcnt vmcnt(6)" ::: "memory");
    else               asm volatile("s_waitcnt vmcnt(0)" ::: "memory");
    __builtin_amdgcn_s_barrier();

    // y-norms for this tile from LDS (lgkm only — keeps vmcnt counted)
    float ysv[4];
#pragma unroll
    for (int cb = 0; cb < 4; ++cb) {
      unsigned u = *(const unsigned short*)(&LDS[YS_OFF + ((t * 64 + cb * 16 + sub) << 1)]);
      ysv[cb] = (float)u * (1.0f / 65535.0f);
    }

    f32x4 acc[2][4];
#pragma unroll
    for (int rb = 0; rb < 2; ++rb)
#pragma unroll
      for (int cb = 0; cb < 4; ++cb) acc[rb][cb] = (f32x4){0.f, 0.f, 0.f, 0.f};

    const unsigned char* br = LDS + bufo + lane * 16;
    __builtin_amdgcn_s_setprio(1);
#pragma unroll
    for (int kp = 0; kp < KP; ++kp) {
#pragma unroll
      for (int cb = 0; cb < 4; ++cb) {
        i64x2 b = *(const i64x2*)(br + (cb * KP + kp) * 1024);
        acc[0][cb] = __builtin_amdgcn_mfma_f32_16x16x32_fp8_fp8(af0[2 * kp], b.x, acc[0][cb], 0, 0, 0);
        acc[1][cb] = __builtin_amdgcn_mfma_f32_16x16x32_fp8_fp8(af1[2 * kp], b.x, acc[1][cb], 0, 0, 0);
        acc[0][cb] = __builtin_amdgcn_mfma_f32_16x16x32_fp8_fp8(af0[2 * kp + 1], b.y, acc[0][cb], 0, 0, 0);
        acc[1][cb] = __builtin_amdgcn_mfma_f32_16x16x32_fp8_fp8(af1[2 * kp + 1], b.y, acc[1][cb], 0, 0, 0);
      }
    }
    __builtin_amdgcn_s_setprio(0);
    __builtin_amdgcn_s_barrier();  // all waves done reading buf[t&1]

    // refill buf[t&1] with tile t+2; latency hides under topk below
    if (t + 2 < TILES) {
#pragma unroll
      for (int q = 0; q < KP; ++q)
        __builtin_amdgcn_global_load_lds(
            (const __attribute__((address_space(1))) void*)(bsrc + q * 64),
            (__attribute__((address_space(3))) void*)(LDS + bufo + (w * KP + q) * 1024),
            16, 0, 0);
      bsrc += 24576;
    }

    // ---- topk update (pure VALU) ----
#pragma unroll
    for (int cb = 0; cb < 4; ++cb) {
#pragma unroll
      for (int i = 0; i < 4; ++i) {
        float d2a = fmaf(acc[0][cb][i], M2S, xs0[i] + ysv[cb]);
        float d2b = fmaf(acc[1][cb][i], M2S, xs1[i] + ysv[cb]);
        unsigned dpu;
        asm("v_cvt_pknorm_u16_f32 %0, %1, %2" : "=v"(dpu) : "v"(d2a), "v"(d2b));
        u16x2 dp = __builtin_bit_cast(u16x2, dpu);
#pragma unroll
        for (int j = 8; j >= 1; --j)
          tkp[i][j] = __builtin_elementwise_min(
              tkp[i][j], __builtin_elementwise_max(dp, tkp[i][j - 1]));
        tkp[i][0] = __builtin_elementwise_min(tkp[i][0], dp);
      }
    }
  }

  // ---- unpack + per-row merge across 16 sub-lanes; write f32 d^2 partials ----
  float* pbase = part + (size_t)mq * N_ROWS * K_NB;
#pragma unroll
  for (int i = 0; i < 4; ++i) {
    unsigned ta[9], tb[9];
#pragma unroll
    for (int j = 0; j < 9; ++j) { ta[j] = tkp[i][j].x; tb[j] = tkp[i][j].y; }
    merge16i(ta, pbase + (size_t)(wrow0 + grp * 4 + i) * K_NB, sub);
    merge16i(tb, pbase + (size_t)(wrow0 + 16 + grp * 4 + i) * K_NB, sub);
  }
}

// ------- merge the four M-quarter partials, sqrt, final output -------
__global__ __launch_bounds__(256) void FAPM_merge4(
    const float* __restrict__ part, float* __restrict__ out) {
  const int r = blockIdx.x * 256 + threadIdx.x;
  float l[4][9];
#pragma unroll
  for (int q = 0; q < 4; ++q)
#pragma unroll
    for (int j = 0; j < 9; ++j)
      l[q][j] = part[(size_t)q * N_ROWS * K_NB + (size_t)r * K_NB + j];
#pragma unroll
  for (int s = 0; s < K_NB; ++s) {
    float m = fminf(fminf(l[0][0], l[1][0]), fminf(l[2][0], l[3][0]));
    out[(size_t)r * K_NB + s] = sqrtf(fmaxf(m, 0.f));
    bool t0 = (l[0][0] == m);
    bool t1 = (l[1][0] == m) && !t0;
    bool t2 = (l[2][0] == m) && !t0 && !t1;
    bool t3 = !(t0 || t1 || t2);
#pragma unroll
    for (int j = 0; j < 8; ++j) {
      l[0][j] = t0 ? l[0][j + 1] : l[0][j];
      l[1][j] = t1 ? l[1][j + 1] : l[1][j];
      l[2][j] = t2 ? l[2][j + 1] : l[2][j];
      l[3][j] = t3 ? l[3][j + 1] : l[3][j];
    }
    l[0][8] = t0 ? BIGF : l[0][8];
    l[1][8] = t1 ? BIGF : l[1][8];
    l[2][8] = t2 ? BIGF : l[2][8];
    l[3][8] = t3 ? BIGF : l[3][8];
  }
}

extern "C" void kernel_launch(void* const* d_in, const int* in_sizes, int n_in,
                              void* d_out, int out_size, void* d_ws, size_t ws_size,
                              hipStream_t stream) {
  const float* emb = (const float*)d_in[0];
  const float* mem = (const float*)d_in[1];
  float* out = (float*)d_out;
  char* ws = (char*)d_ws;
  size_t offA = 0;
  size_t offB = offA + (size_t)N_ROWS * D_DIM;       // A8: 12,582,912
  size_t offX = offB + (size_t)M_ROWS * D_DIM;       // B8: +3,145,728
  size_t offY = offX + (size_t)N_ROWS * 4;           // +131,072
  size_t offP = offY + (size_t)M_ROWS * 4;           // +32,768
  // partials: 4 quarters x N x 9 f32 = 4,718,592  (total ~20.6 MB)
  unsigned char* A8 = (unsigned char*)(ws + offA);
  unsigned char* B8 = (unsigned char*)(ws + offB);
  float* xn = (float*)(ws + offX);
  float* yn = (float*)(ws + offY);
  float* part = (float*)(ws + offP);

  FAPM_prep8<<<(N_ROWS + M_ROWS) / 4, 256, 0, stream>>>(
      emb, mem, (unsigned*)A8, (unsigned*)B8, xn, yn);
  FAPM_fused<<<(N_ROWS / 128) * 4, 256, 0, stream>>>(A8, B8, xn, yn, part);
  FAPM_merge4<<<N_ROWS / 256, 256, 0, stream>>>(part, out);
}